// Round 6
// baseline (138.081 us; speedup 1.0000x reference)
//
#include <hip/hip_runtime.h>
#include <cmath>

#define BATCH 8
#define SEQ   2048
#define NEMB  2048
#define HD    128
#define NROWS (BATCH * SEQ)   // 16384

typedef __bf16 v8bf __attribute__((ext_vector_type(8)));
typedef float  f32x4 __attribute__((ext_vector_type(4)));

union U8 { v8bf v; __bf16 b[8]; unsigned short e[8]; };

__device__ inline void async16(void* lds, const void* g) {
  __builtin_amdgcn_global_load_lds(
      (const __attribute__((address_space(1))) unsigned int*)g,
      (__attribute__((address_space(3))) unsigned int*)lds, 16, 0, 0);
}

__device__ inline v8bf cvt8(float4 a, float4 b) {
  U8 u;
  u.b[0] = (__bf16)a.x; u.b[1] = (__bf16)a.y; u.b[2] = (__bf16)a.z; u.b[3] = (__bf16)a.w;
  u.b[4] = (__bf16)b.x; u.b[5] = (__bf16)b.y; u.b[6] = (__bf16)b.z; u.b[7] = (__bf16)b.w;
  return u.v;
}

// ---------------- W fp32 -> bf16 (3 x 128 x 2048) ----------------
__global__ __launch_bounds__(256) void wconv_kernel(
    const float* __restrict__ Wq, const float* __restrict__ Wk,
    const float* __restrict__ Wv, __bf16* __restrict__ out) {
  const int id = blockIdx.x;                 // 3 * 64 blocks
  const int proj = id >> 6, blk = id & 63;
  const float* __restrict__ W = proj == 0 ? Wq : proj == 1 ? Wk : Wv;
  __bf16* __restrict__ o = out + (size_t)proj * (HD * NEMB);
  const int base = blk * 4096 + threadIdx.x * 16;
  const float4* s = (const float4*)(W + base);
  float4 f0 = s[0], f1 = s[1], f2 = s[2], f3 = s[3];
  *(v8bf*)(o + base) = cvt8(f0, f1);
  *(v8bf*)(o + base + 8) = cvt8(f2, f3);
}

// ---------------- QKV projection ----------------
// Mtile=64, Ntile=128, BK=64, 4 waves (2x2) of 32x64. LDS-pipe-optimized:
// A staged as BF16 (reg: 4x float4 -> cvt -> 2x ds_write_b128, swizzled),
// B staged via global_load_lds. LDS = 8 KB (A) + 16 KB (B) -> 3 blocks/CU.
// Next step's A global loads issued under COMPUTE (latency hidden).
// grid: 256 mt * 3 proj = 768; XCD-chunked swizzle (chunk 96).
__global__ __launch_bounds__(256, 3) void qkv_proj_kernel(
    const float* __restrict__ x, const __bf16* __restrict__ Wb,
    const float* __restrict__ bq, const float* __restrict__ bk,
    const float* __restrict__ bv,
    __bf16* __restrict__ Qb, __bf16* __restrict__ Kb, __bf16* __restrict__ Vb)
{
  const int bid0 = blockIdx.x;
  const int bid = ((bid0 & 7) * 96) + (bid0 >> 3);   // 768 % 8 == 0
  const int mt = bid / 3;
  const int proj = bid % 3;
  const __bf16* __restrict__ W = Wb + (size_t)proj * (HD * NEMB);
  const float* __restrict__ bias = proj == 0 ? bq : proj == 1 ? bk : bv;
  __bf16* __restrict__ Out = proj == 0 ? Qb : proj == 1 ? Kb : Vb;
  const int m0 = mt * 64;

  __shared__ __bf16 Asm[64 * 64];    // bf16 x tile, 128B rows, swizzled (8 KB)
  __shared__ __bf16 Bsm[128 * 64];   // bf16 W tile, 128B rows, swizzled (16 KB)

  const int t = threadIdx.x, lane = t & 63, w = t >> 6;
  const int wm = w >> 1, wn = w & 1;          // wave: 32 rows x 64 cols
  const int hi = lane >> 4, lo = lane & 15;

  // A reg-staging map: thread t -> row = t>>2, quarter q = t&3 (16 fp32)
  const int arow = t >> 2, aq = t & 3;
  const float* axp = x + (size_t)(m0 + arow) * NEMB + aq * 16;
  char* aw0 = (char*)Asm + arow * 128 + (((aq * 2)     ^ (arow & 7)) << 4);
  char* aw1 = (char*)Asm + arow * 128 + (((aq * 2 + 1) ^ (arow & 7)) << 4);

  // B DMA staging (inverse-swizzled source, linear LDS dest)
  const __bf16* pb[4];
#pragma unroll
  for (int i = 0; i < 4; ++i) {   // 16 chunks of 1KB (8 rows x 128B each)
    const int r = (w * 4 + i) * 8 + (lane >> 3);
    const int c = (lane & 7) ^ (r & 7);
    pb[i] = W + (size_t)r * NEMB + c * 8;
  }

  f32x4 acc[2][4];
  const f32x4 fz = {0.f, 0.f, 0.f, 0.f};
#pragma unroll
  for (int m = 0; m < 2; ++m)
#pragma unroll
    for (int n = 0; n < 4; ++n) acc[m][n] = fz;

  float4 fa0, fa1, fa2, fa3;
  auto ALOAD = [&](int tt) {
    const float* p = axp + tt * 64;
    fa0 = *(const float4*)(p);
    fa1 = *(const float4*)(p + 4);
    fa2 = *(const float4*)(p + 8);
    fa3 = *(const float4*)(p + 12);
  };

  const int NT = NEMB / 64;  // 32
  ALOAD(0);
  for (int tt = 0; tt < NT; ++tt) {
    __syncthreads();   // previous compute done -> safe to overwrite tiles
    {
      const int k0 = tt * 64;
#pragma unroll
      for (int i = 0; i < 4; ++i) async16((char*)Bsm + (w * 4 + i) * 1024, pb[i] + k0);
      *(v8bf*)aw0 = cvt8(fa0, fa1);
      *(v8bf*)aw1 = cvt8(fa2, fa3);
    }
    __syncthreads();   // B DMA drained + A writes visible
    if (tt + 1 < NT) ALOAD(tt + 1);   // fly during compute; drained at next barrier

#pragma unroll
    for (int kk = 0; kk < 2; ++kk) {
      v8bf a[2], b[4];
      const int kc = kk * 4 + hi;     // 16B chunk index 0..7
#pragma unroll
      for (int m = 0; m < 2; ++m) {
        const int r = wm * 32 + m * 16 + lo;
        a[m] = *(const v8bf*)((const char*)Asm + r * 128 + ((kc ^ (r & 7)) << 4));
      }
#pragma unroll
      for (int n = 0; n < 4; ++n) {
        const int r = wn * 64 + n * 16 + lo;
        b[n] = *(const v8bf*)((const char*)Bsm + r * 128 + ((kc ^ (r & 7)) << 4));
      }
#pragma unroll
      for (int m = 0; m < 2; ++m)
#pragma unroll
        for (int n = 0; n < 4; ++n)
          acc[m][n] = __builtin_amdgcn_mfma_f32_16x16x32_bf16(a[m], b[n], acc[m][n], 0, 0, 0);
    }
  }

#pragma unroll
  for (int n = 0; n < 4; ++n) {
    const int col = wn * 64 + n * 16 + lo;
    const float bi = bias[col];
#pragma unroll
    for (int m = 0; m < 2; ++m) {
#pragma unroll
      for (int r = 0; r < 4; ++r) {
        const int row = m0 + wm * 32 + m * 16 + hi * 4 + r;
        Out[(size_t)row * HD + col] = (__bf16)(acc[m][n][r] + bi);
      }
    }
  }
}

// ---------------- Flash attention, split-KV x2 ----------------
// grid: 8 batches * 32 q-tiles * 2 kv-halves = 512 blocks, 256 thr.
// Writes unnormalized O + (m,l) partials; combine_kernel merges.
__global__ __launch_bounds__(256) void attn_kernel(
    const __bf16* __restrict__ Qb, const __bf16* __restrict__ Kb,
    const __bf16* __restrict__ Vb, float* __restrict__ Opart,
    float* __restrict__ Ml)
{
  const int bid0 = blockIdx.x;
  const int bid = ((bid0 & 7) << 6) + (bid0 >> 3);   // one batch per XCD
  const int b = bid >> 6;
  const int qs = bid & 63;
  const int qt = qs >> 1;
  const int s  = qs & 1;
  const int q0 = qt * 64;
  const int half = (qt + 2) >> 1;
  const int kv_beg = s ? half : 0;
  const int kv_end = s ? (qt + 1) : half;
  const int nst = kv_end - kv_beg;

  const int t = threadIdx.x, lane = t & 63, w = t >> 6;
  const int hi = lane >> 4, lo = lane & 15;

  __shared__ __bf16 Ksm[2][64 * 128];   // [key][d], 256B rows, swizzled
  __shared__ __bf16 Vtsm[2][128 * 64];  // [d][key], 128B rows, swizzled
  __shared__ __bf16 Psm[4][16 * 64];    // per-wave P, swizzled

  // Q fragments
  v8bf aQ[4];
  {
    const __bf16* qp = Qb + ((size_t)(b * SEQ + q0 + w * 16 + lo)) * HD + hi * 8;
#pragma unroll
    for (int kk = 0; kk < 4; ++kk) aQ[kk] = *(const v8bf*)(qp + kk * 32);
  }

  // K staging sources (global_load_lds, inverse-swizzled source, linear dest)
  const __bf16* kga[4];
#pragma unroll
  for (int i = 0; i < 4; ++i) {
    const int r = (w * 4 + i) * 4 + (lane >> 4);   // key row 0..63
    const int c = (lane & 15) ^ (r & 7);           // 16B chunk within 256B row
    kga[i] = Kb + ((size_t)(b * SEQ) + r) * HD + c * 8;
  }

  // V reg staging mapping
  const int keyg = t >> 4, dg = t & 15;   // keys keyg*4.., d-cols dg*8..
  U8 vv[4];

  f32x4 accO[8];
  const f32x4 fz = {0.f, 0.f, 0.f, 0.f};
#pragma unroll
  for (int n = 0; n < 8; ++n) accO[n] = fz;
  float m_s[4], l_s[4];
#pragma unroll
  for (int r = 0; r < 4; ++r) { m_s[r] = -INFINITY; l_s[r] = 0.f; }

  const float scale = 0.022097086912079608f;  // 1/sqrt(2048)

  if (nst > 0) {
    auto STAGE_K = [&](int kv, int buf) {
      const size_t off = (size_t)kv * 64 * HD;
      char* kb = (char*)&Ksm[buf][0];
#pragma unroll
      for (int i = 0; i < 4; ++i) async16(kb + (w * 4 + i) * 1024, kga[i] + off);
    };
    auto LOAD_V = [&](int kv) {
      const __bf16* vp = Vb + ((size_t)(b * SEQ + kv * 64 + keyg * 4)) * HD + dg * 8;
#pragma unroll
      for (int j = 0; j < 4; ++j) vv[j].v = *(const v8bf*)(vp + (size_t)j * HD);
    };
    auto WRITE_VT = [&](int buf) {
      char* vb2 = (char*)&Vtsm[buf][0];
#pragma unroll
      for (int dd = 0; dd < 8; ++dd) {
        const int d = (dd + dg) & 7;               // rotation: row&7 spans lanes
        ushort4 pk = make_ushort4(vv[0].e[d], vv[1].e[d], vv[2].e[d], vv[3].e[d]);
        const int row = dg * 8 + d;
        *(ushort4*)(vb2 + row * 128 + ((keyg * 8) ^ ((row & 7) << 4))) = pk;
      }
    };

    STAGE_K(kv_beg, 0);
    LOAD_V(kv_beg);
    WRITE_VT(0);
    __syncthreads();   // K DMA drained + Vt visible

    for (int t2 = 0; t2 < nst; ++t2) {
      const int kv = kv_beg + t2;
      const int cur = t2 & 1;
      const bool more = (t2 + 1 < nst);
      if (more) { STAGE_K(kv + 1, cur ^ 1); LOAD_V(kv + 1); }

      // S = Q K^T
      f32x4 accS[4];
#pragma unroll
      for (int n = 0; n < 4; ++n) accS[n] = fz;
      const char* ksm = (const char*)&Ksm[cur][0];
#pragma unroll
      for (int kk = 0; kk < 4; ++kk) {
        const int cb = kk * 64 + hi * 16;
        v8bf bk[4];
#pragma unroll
        for (int n = 0; n < 4; ++n) {
          const int r = n * 16 + lo;
          bk[n] = *(const v8bf*)(ksm + r * 256 + (cb ^ ((r & 7) << 4)));
        }
#pragma unroll
        for (int n = 0; n < 4; ++n)
          accS[n] = __builtin_amdgcn_mfma_f32_16x16x32_bf16(aQ[kk], bk[n], accS[n], 0, 0, 0);
      }

      // scale + causal mask (diagonal tile only)
      float sv[4][4];
      const bool diag = (kv == qt);
#pragma unroll
      for (int n = 0; n < 4; ++n)
#pragma unroll
        for (int r = 0; r < 4; ++r) {
          float v = accS[n][r] * scale;
          if (diag) {
            const int key = kv * 64 + n * 16 + lo;
            const int qr = q0 + w * 16 + hi * 4 + r;
            if (key > qr) v = -INFINITY;
          }
          sv[n][r] = v;
        }

      // online softmax
      float mx[4];
#pragma unroll
      for (int r = 0; r < 4; ++r) {
        mx[r] = fmaxf(fmaxf(sv[0][r], sv[1][r]), fmaxf(sv[2][r], sv[3][r]));
#pragma unroll
        for (int off = 1; off < 16; off <<= 1)
          mx[r] = fmaxf(mx[r], __shfl_xor(mx[r], off));
      }
      float corr[4], p[4][4], rs[4];
#pragma unroll
      for (int r = 0; r < 4; ++r) {
        const float mnew = fmaxf(m_s[r], mx[r]);
        corr[r] = __expf(m_s[r] - mnew);
        m_s[r] = mnew;
        rs[r] = 0.f;
      }
#pragma unroll
      for (int n = 0; n < 4; ++n)
#pragma unroll
        for (int r = 0; r < 4; ++r) {
          p[n][r] = __expf(sv[n][r] - m_s[r]);
          rs[r] += p[n][r];
        }
#pragma unroll
      for (int r = 0; r < 4; ++r) {
#pragma unroll
        for (int off = 1; off < 16; off <<= 1) rs[r] += __shfl_xor(rs[r], off);
        l_s[r] = l_s[r] * corr[r] + rs[r];
      }
#pragma unroll
      for (int n = 0; n < 8; ++n)
#pragma unroll
        for (int r = 0; r < 4; ++r) accO[n][r] *= corr[r];

      // P -> per-wave LDS (bf16)
#pragma unroll
      for (int n = 0; n < 4; ++n)
#pragma unroll
        for (int r = 0; r < 4; ++r) {
          const int row = hi * 4 + r;
          __bf16 h = (__bf16)p[n][r];
          *(unsigned short*)((char*)&Psm[w][0] + row * 128 +
                             (((n * 16 + lo) * 2) ^ ((row & 7) << 4))) =
              __builtin_bit_cast(unsigned short, h);
        }

      // write next tile's Vt (other buffer) before PV; overlaps with PV's pipe
      if (more) WRITE_VT(cur ^ 1);

      // O += P V
      const char* vsm = (const char*)&Vtsm[cur][0];
#pragma unroll
      for (int k2 = 0; k2 < 2; ++k2) {
        const int cb = k2 * 64 + hi * 16;
        const v8bf aP = *(const v8bf*)((const char*)&Psm[w][0] + lo * 128 + (cb ^ ((lo & 7) << 4)));
#pragma unroll
        for (int n = 0; n < 8; ++n) {
          const int r = n * 16 + lo;
          const v8bf bv = *(const v8bf*)(vsm + r * 128 + (cb ^ ((r & 7) << 4)));
          accO[n] = __builtin_amdgcn_mfma_f32_16x16x32_bf16(aP, bv, accO[n], 0, 0, 0);
        }
      }
      if (more) __syncthreads();   // next K resident, Vt[cur^1] visible, reads of cur done
    }
  }

  // store partials (unnormalized O, m, l)
#pragma unroll
  for (int r = 0; r < 4; ++r) {
    const int qr = q0 + w * 16 + hi * 4 + r;
    float* op = Opart + ((size_t)s * NROWS + b * SEQ + qr) * HD + lo;
#pragma unroll
    for (int n = 0; n < 8; ++n) op[n * 16] = accO[n][r];
    if (lo == 0) {
      float* mlp = Ml + ((size_t)s * NROWS + b * SEQ + qr) * 2;
      mlp[0] = m_s[r];
      mlp[1] = l_s[r];
    }
  }
}

// ---------------- combine the two KV-half partials ----------------
__global__ __launch_bounds__(256) void combine_kernel(
    const float* __restrict__ Opart, const float* __restrict__ Ml,
    float* __restrict__ out)
{
  const int idx = blockIdx.x * 256 + threadIdx.x;  // 0..32767
  const int row = idx >> 1, h = idx & 1;
  const float m0 = Ml[(size_t)row * 2],           l0 = Ml[(size_t)row * 2 + 1];
  const float m1 = Ml[((size_t)NROWS + row) * 2], l1 = Ml[((size_t)NROWS + row) * 2 + 1];
  const float M = fmaxf(m0, m1);
  const float e0 = __expf(m0 - M), e1 = __expf(m1 - M);
  const float inv = 1.f / (l0 * e0 + l1 * e1);
  const float4* p0 = (const float4*)(Opart + (size_t)row * HD + h * 64);
  const float4* p1 = (const float4*)(Opart + ((size_t)NROWS + row) * HD + h * 64);
  float4* po = (float4*)(out + (size_t)row * HD + h * 64);
#pragma unroll
  for (int j = 0; j < 16; ++j) {
    float4 a = p0[j], c = p1[j];
    float4 r;
    r.x = (a.x * e0 + c.x * e1) * inv;
    r.y = (a.y * e0 + c.y * e1) * inv;
    r.z = (a.z * e0 + c.z * e1) * inv;
    r.w = (a.w * e0 + c.w * e1) * inv;
    po[j] = r;
  }
}

extern "C" void kernel_launch(void* const* d_in, const int* in_sizes, int n_in,
                              void* d_out, int out_size, void* d_ws, size_t ws_size,
                              hipStream_t stream) {
  const float* x  = (const float*)d_in[0];
  const float* Wq = (const float*)d_in[1];
  const float* bq = (const float*)d_in[2];
  const float* Wk = (const float*)d_in[3];
  const float* bk = (const float*)d_in[4];
  const float* Wv = (const float*)d_in[5];
  const float* bv = (const float*)d_in[6];
  float* out = (float*)d_out;

  // workspace layout (~30 MiB)
  __bf16* Qb = (__bf16*)d_ws;                        // 16384x128 bf16 each
  __bf16* Kb = Qb + (size_t)NROWS * HD;
  __bf16* Vb = Kb + (size_t)NROWS * HD;
  __bf16* Wb = Vb + (size_t)NROWS * HD;              // 3 x 128 x 2048 bf16
  float*  Opart = (float*)(Wb + (size_t)3 * HD * NEMB);  // 2 x 16384 x 128 fp32
  float*  Ml    = Opart + (size_t)2 * NROWS * HD;        // 2 x 16384 x 2 fp32

  wconv_kernel<<<dim3(3 * 64), dim3(256), 0, stream>>>(Wq, Wk, Wv, Wb);
  qkv_proj_kernel<<<dim3(256 * 3), dim3(256), 0, stream>>>(
      x, Wb, bq, bk, bv, Qb, Kb, Vb);
  attn_kernel<<<dim3(BATCH * 32 * 2), dim3(256), 0, stream>>>(Qb, Kb, Vb, Opart, Ml);
  combine_kernel<<<dim3(NROWS * 2 / 256), dim3(256), 0, stream>>>(Opart, Ml, out);
}

// Round 7
// 124.934 us; speedup vs baseline: 1.1052x; 1.1052x over previous
//
#include <hip/hip_runtime.h>
#include <cmath>

#define BATCH 8
#define SEQ   2048
#define NEMB  2048
#define HD    128
#define NROWS (BATCH * SEQ)   // 16384

typedef __bf16 v8bf __attribute__((ext_vector_type(8)));
typedef float  f32x4 __attribute__((ext_vector_type(4)));

union U8 { v8bf v; __bf16 b[8]; unsigned short e[8]; };
union F4 { f32x4 v; float f[4]; };

__device__ inline void async16(void* lds, const void* g) {
  __builtin_amdgcn_global_load_lds(
      (const __attribute__((address_space(1))) unsigned int*)g,
      (__attribute__((address_space(3))) unsigned int*)lds, 16, 0, 0);
}

__device__ inline v8bf cvt8(float4 a, float4 b) {
  U8 u;
  u.b[0] = (__bf16)a.x; u.b[1] = (__bf16)a.y; u.b[2] = (__bf16)a.z; u.b[3] = (__bf16)a.w;
  u.b[4] = (__bf16)b.x; u.b[5] = (__bf16)b.y; u.b[6] = (__bf16)b.z; u.b[7] = (__bf16)b.w;
  return u.v;
}

// ---------------- W fp32 -> bf16 (3 x 128 x 2048) ----------------
__global__ __launch_bounds__(256) void wconv_kernel(
    const float* __restrict__ Wq, const float* __restrict__ Wk,
    const float* __restrict__ Wv, __bf16* __restrict__ out) {
  const int id = blockIdx.x;                 // 3 * 64 blocks
  const int proj = id >> 6, blk = id & 63;
  const float* __restrict__ W = proj == 0 ? Wq : proj == 1 ? Wk : Wv;
  __bf16* __restrict__ o = out + (size_t)proj * (HD * NEMB);
  const int base = blk * 4096 + threadIdx.x * 16;
  const float4* s = (const float4*)(W + base);
  float4 f0 = s[0], f1 = s[1], f2 = s[2], f3 = s[3];
  *(v8bf*)(o + base) = cvt8(f0, f1);
  *(v8bf*)(o + base + 8) = cvt8(f2, f3);
}

// ---------------- QKV projection (round-3 structure: pure DMA staging) ----
// Mtile=64, Ntile=128, BK=64, 4 waves (2x2 of 32x64).
//   A tile fp32 [64][64]  (16 KB, 256B rows, 16B-chunk XOR swizzle) via DMA
//   B tile bf16 [128][64] (16 KB, 128B rows, same swizzle) via DMA
// LDS dest linear, global source inverse-swizzled; cvt fp32->bf16 at
// fragment-read time. 32 KB LDS -> 3 blocks/CU. 2 barriers/step.
__global__ __launch_bounds__(256, 3) void qkv_proj_kernel(
    const float* __restrict__ x, const __bf16* __restrict__ Wb,
    const float* __restrict__ bq, const float* __restrict__ bk,
    const float* __restrict__ bv,
    __bf16* __restrict__ Qb, __bf16* __restrict__ Kb, __bf16* __restrict__ Vb)
{
  const int bid0 = blockIdx.x;
  const int bid = ((bid0 & 7) * 96) + (bid0 >> 3);   // 768 % 8 == 0
  const int mt = bid / 3;
  const int proj = bid % 3;
  const __bf16* __restrict__ W = Wb + (size_t)proj * (HD * NEMB);
  const float* __restrict__ bias = proj == 0 ? bq : proj == 1 ? bk : bv;
  __bf16* __restrict__ Out = proj == 0 ? Qb : proj == 1 ? Kb : Vb;
  const int m0 = mt * 64;

  __shared__ float  Asm[64 * 64];    // fp32 x tile
  __shared__ __bf16 Bsm[128 * 64];   // bf16 W tile

  const int t = threadIdx.x, lane = t & 63, w = t >> 6;
  const int wm = w >> 1, wn = w & 1;
  const int hi = lane >> 4, lo = lane & 15;

  // staging pointers: 4 A-slots + 4 B-slots per wave, 1 KB each
  const float* pa[4];
  const __bf16* pb[4];
  char* la[4];
  char* lb[4];
#pragma unroll
  for (int i = 0; i < 4; ++i) {
    {  // A chunk (w*4+i): 4 rows x 256B; lane covers (row=lane>>4, col16=lane&15)
      const int r = (w * 4 + i) * 4 + (lane >> 4);
      const int c = (lane & 15) ^ (r & 7);         // inverse swizzle
      pa[i] = x + (size_t)(m0 + r) * NEMB + c * 4;
      la[i] = (char*)Asm + (w * 4 + i) * 1024;
    }
    {  // B chunk: 8 rows x 128B; lane covers (row=lane>>3, col16=lane&7)
      const int r = (w * 4 + i) * 8 + (lane >> 3);
      const int c = (lane & 7) ^ (r & 7);
      pb[i] = W + (size_t)r * NEMB + c * 8;
      lb[i] = (char*)Bsm + (w * 4 + i) * 1024;
    }
  }

  f32x4 acc[2][4];
  const f32x4 fz = {0.f, 0.f, 0.f, 0.f};
#pragma unroll
  for (int m = 0; m < 2; ++m)
#pragma unroll
    for (int n = 0; n < 4; ++n) acc[m][n] = fz;

  for (int tt = 0; tt < NEMB / 64; ++tt) {
    const int k0 = tt * 64;
    __syncthreads();   // previous compute done -> safe to overwrite tiles
#pragma unroll
    for (int i = 0; i < 4; ++i) async16(la[i], pa[i] + k0);
#pragma unroll
    for (int i = 0; i < 4; ++i) async16(lb[i], pb[i] + k0);
    __syncthreads();   // drain: tile tt resident

#pragma unroll
    for (int kk = 0; kk < 2; ++kk) {
      v8bf a[2], b[4];
#pragma unroll
      for (int m = 0; m < 2; ++m) {
        const int r = wm * 32 + m * 16 + lo;
        const int s = kk * 8 + hi * 2;             // fp32 16B-chunk pair s, s+1
        const char* rowp = (const char*)Asm + r * 256;
        F4 a0, a1;
        a0.v = *(const f32x4*)(rowp + (((s)     ^ (r & 7)) << 4));
        a1.v = *(const f32x4*)(rowp + (((s + 1) ^ (r & 7)) << 4));
        U8 u;
#pragma unroll
        for (int q = 0; q < 4; ++q) {
          u.b[q]     = (__bf16)a0.f[q];
          u.b[q + 4] = (__bf16)a1.f[q];
        }
        a[m] = u.v;
      }
#pragma unroll
      for (int n = 0; n < 4; ++n) {
        const int r = wn * 64 + n * 16 + lo;
        const int kc = kk * 4 + hi;
        b[n] = *(const v8bf*)((const char*)Bsm + r * 128 + ((kc ^ (r & 7)) << 4));
      }
#pragma unroll
      for (int m = 0; m < 2; ++m)
#pragma unroll
        for (int n = 0; n < 4; ++n)
          acc[m][n] = __builtin_amdgcn_mfma_f32_16x16x32_bf16(a[m], b[n], acc[m][n], 0, 0, 0);
    }
  }

#pragma unroll
  for (int n = 0; n < 4; ++n) {
    const int col = wn * 64 + n * 16 + lo;
    const float bi = bias[col];
#pragma unroll
    for (int m = 0; m < 2; ++m) {
#pragma unroll
      for (int r = 0; r < 4; ++r) {
        const int row = m0 + wm * 32 + m * 16 + hi * 4 + r;
        Out[(size_t)row * HD + col] = (__bf16)(acc[m][n][r] + bi);
      }
    }
  }
}

// ---------------- Flash attention, split-KV x2 ----------------
// grid: 8 batches * 32 q-tiles * 2 kv-halves = 512 blocks, 256 thr.
// Writes unnormalized O + (m,l) partials; combine_kernel merges.
__global__ __launch_bounds__(256) void attn_kernel(
    const __bf16* __restrict__ Qb, const __bf16* __restrict__ Kb,
    const __bf16* __restrict__ Vb, float* __restrict__ Opart,
    float* __restrict__ Ml)
{
  const int bid0 = blockIdx.x;
  const int bid = ((bid0 & 7) << 6) + (bid0 >> 3);   // one batch per XCD
  const int b = bid >> 6;
  const int qs = bid & 63;
  const int qt = qs >> 1;
  const int s  = qs & 1;
  const int q0 = qt * 64;
  const int half = (qt + 2) >> 1;
  const int kv_beg = s ? half : 0;
  const int kv_end = s ? (qt + 1) : half;
  const int nst = kv_end - kv_beg;

  const int t = threadIdx.x, lane = t & 63, w = t >> 6;
  const int hi = lane >> 4, lo = lane & 15;

  __shared__ __bf16 Ksm[2][64 * 128];   // [key][d], 256B rows, swizzled
  __shared__ __bf16 Vtsm[2][128 * 64];  // [d][key], 128B rows, swizzled
  __shared__ __bf16 Psm[4][16 * 64];    // per-wave P, swizzled

  // Q fragments
  v8bf aQ[4];
  {
    const __bf16* qp = Qb + ((size_t)(b * SEQ + q0 + w * 16 + lo)) * HD + hi * 8;
#pragma unroll
    for (int kk = 0; kk < 4; ++kk) aQ[kk] = *(const v8bf*)(qp + kk * 32);
  }

  // K staging sources (global_load_lds, inverse-swizzled source, linear dest)
  const __bf16* kga[4];
#pragma unroll
  for (int i = 0; i < 4; ++i) {
    const int r = (w * 4 + i) * 4 + (lane >> 4);   // key row 0..63
    const int c = (lane & 15) ^ (r & 7);           // 16B chunk within 256B row
    kga[i] = Kb + ((size_t)(b * SEQ) + r) * HD + c * 8;
  }

  // V reg staging mapping
  const int keyg = t >> 4, dg = t & 15;   // keys keyg*4.., d-cols dg*8..
  U8 vv[4];

  f32x4 accO[8];
  const f32x4 fz = {0.f, 0.f, 0.f, 0.f};
#pragma unroll
  for (int n = 0; n < 8; ++n) accO[n] = fz;
  float m_s[4], l_s[4];
#pragma unroll
  for (int r = 0; r < 4; ++r) { m_s[r] = -INFINITY; l_s[r] = 0.f; }

  const float scale = 0.022097086912079608f;  // 1/sqrt(2048)

  if (nst > 0) {
    auto STAGE_K = [&](int kv, int buf) {
      const size_t off = (size_t)kv * 64 * HD;
      char* kb = (char*)&Ksm[buf][0];
#pragma unroll
      for (int i = 0; i < 4; ++i) async16(kb + (w * 4 + i) * 1024, kga[i] + off);
    };
    auto LOAD_V = [&](int kv) {
      const __bf16* vp = Vb + ((size_t)(b * SEQ + kv * 64 + keyg * 4)) * HD + dg * 8;
#pragma unroll
      for (int j = 0; j < 4; ++j) vv[j].v = *(const v8bf*)(vp + (size_t)j * HD);
    };
    auto WRITE_VT = [&](int buf) {
      char* vb2 = (char*)&Vtsm[buf][0];
#pragma unroll
      for (int dd = 0; dd < 8; ++dd) {
        const int d = (dd + dg) & 7;               // rotation: row&7 spans lanes
        ushort4 pk = make_ushort4(vv[0].e[d], vv[1].e[d], vv[2].e[d], vv[3].e[d]);
        const int row = dg * 8 + d;
        *(ushort4*)(vb2 + row * 128 + ((keyg * 8) ^ ((row & 7) << 4))) = pk;
      }
    };

    STAGE_K(kv_beg, 0);
    LOAD_V(kv_beg);
    WRITE_VT(0);
    __syncthreads();   // K DMA drained + Vt visible

    for (int t2 = 0; t2 < nst; ++t2) {
      const int kv = kv_beg + t2;
      const int cur = t2 & 1;
      const bool more = (t2 + 1 < nst);
      if (more) { STAGE_K(kv + 1, cur ^ 1); LOAD_V(kv + 1); }

      // S = Q K^T
      f32x4 accS[4];
#pragma unroll
      for (int n = 0; n < 4; ++n) accS[n] = fz;
      const char* ksm = (const char*)&Ksm[cur][0];
#pragma unroll
      for (int kk = 0; kk < 4; ++kk) {
        const int cb = kk * 64 + hi * 16;
        v8bf bk[4];
#pragma unroll
        for (int n = 0; n < 4; ++n) {
          const int r = n * 16 + lo;
          bk[n] = *(const v8bf*)(ksm + r * 256 + (cb ^ ((r & 7) << 4)));
        }
#pragma unroll
        for (int n = 0; n < 4; ++n)
          accS[n] = __builtin_amdgcn_mfma_f32_16x16x32_bf16(aQ[kk], bk[n], accS[n], 0, 0, 0);
      }

      // scale + causal mask (diagonal tile only)
      float sv[4][4];
      const bool diag = (kv == qt);
#pragma unroll
      for (int n = 0; n < 4; ++n)
#pragma unroll
        for (int r = 0; r < 4; ++r) {
          float v = accS[n][r] * scale;
          if (diag) {
            const int key = kv * 64 + n * 16 + lo;
            const int qr = q0 + w * 16 + hi * 4 + r;
            if (key > qr) v = -INFINITY;
          }
          sv[n][r] = v;
        }

      // online softmax
      float mx[4];
#pragma unroll
      for (int r = 0; r < 4; ++r) {
        mx[r] = fmaxf(fmaxf(sv[0][r], sv[1][r]), fmaxf(sv[2][r], sv[3][r]));
#pragma unroll
        for (int off = 1; off < 16; off <<= 1)
          mx[r] = fmaxf(mx[r], __shfl_xor(mx[r], off));
      }
      float corr[4], p[4][4], rs[4];
#pragma unroll
      for (int r = 0; r < 4; ++r) {
        const float mnew = fmaxf(m_s[r], mx[r]);
        corr[r] = __expf(m_s[r] - mnew);
        m_s[r] = mnew;
        rs[r] = 0.f;
      }
#pragma unroll
      for (int n = 0; n < 4; ++n)
#pragma unroll
        for (int r = 0; r < 4; ++r) {
          p[n][r] = __expf(sv[n][r] - m_s[r]);
          rs[r] += p[n][r];
        }
#pragma unroll
      for (int r = 0; r < 4; ++r) {
#pragma unroll
        for (int off = 1; off < 16; off <<= 1) rs[r] += __shfl_xor(rs[r], off);
        l_s[r] = l_s[r] * corr[r] + rs[r];
      }
#pragma unroll
      for (int n = 0; n < 8; ++n)
#pragma unroll
        for (int r = 0; r < 4; ++r) accO[n][r] *= corr[r];

      // P -> per-wave LDS (bf16)
#pragma unroll
      for (int n = 0; n < 4; ++n)
#pragma unroll
        for (int r = 0; r < 4; ++r) {
          const int row = hi * 4 + r;
          __bf16 h = (__bf16)p[n][r];
          *(unsigned short*)((char*)&Psm[w][0] + row * 128 +
                             (((n * 16 + lo) * 2) ^ ((row & 7) << 4))) =
              __builtin_bit_cast(unsigned short, h);
        }

      // write next tile's Vt (other buffer) before PV; overlaps with PV's pipe
      if (more) WRITE_VT(cur ^ 1);

      // O += P V
      const char* vsm = (const char*)&Vtsm[cur][0];
#pragma unroll
      for (int k2 = 0; k2 < 2; ++k2) {
        const int cb = k2 * 64 + hi * 16;
        const v8bf aP = *(const v8bf*)((const char*)&Psm[w][0] + lo * 128 + (cb ^ ((lo & 7) << 4)));
#pragma unroll
        for (int n = 0; n < 8; ++n) {
          const int r = n * 16 + lo;
          const v8bf bv = *(const v8bf*)(vsm + r * 128 + (cb ^ ((r & 7) << 4)));
          accO[n] = __builtin_amdgcn_mfma_f32_16x16x32_bf16(aP, bv, accO[n], 0, 0, 0);
        }
      }
      if (more) __syncthreads();   // next K resident, Vt[cur^1] visible, reads of cur done
    }
  }

  // store partials (unnormalized O, m, l)
#pragma unroll
  for (int r = 0; r < 4; ++r) {
    const int qr = q0 + w * 16 + hi * 4 + r;
    float* op = Opart + ((size_t)s * NROWS + b * SEQ + qr) * HD + lo;
#pragma unroll
    for (int n = 0; n < 8; ++n) op[n * 16] = accO[n][r];
    if (lo == 0) {
      float* mlp = Ml + ((size_t)s * NROWS + b * SEQ + qr) * 2;
      mlp[0] = m_s[r];
      mlp[1] = l_s[r];
    }
  }
}

// ---------------- combine the two KV-half partials ----------------
__global__ __launch_bounds__(256) void combine_kernel(
    const float* __restrict__ Opart, const float* __restrict__ Ml,
    float* __restrict__ out)
{
  const int idx = blockIdx.x * 256 + threadIdx.x;  // 0..32767
  const int row = idx >> 1, h = idx & 1;
  const float m0 = Ml[(size_t)row * 2],           l0 = Ml[(size_t)row * 2 + 1];
  const float m1 = Ml[((size_t)NROWS + row) * 2], l1 = Ml[((size_t)NROWS + row) * 2 + 1];
  const float M = fmaxf(m0, m1);
  const float e0 = __expf(m0 - M), e1 = __expf(m1 - M);
  const float inv = 1.f / (l0 * e0 + l1 * e1);
  const float4* p0 = (const float4*)(Opart + (size_t)row * HD + h * 64);
  const float4* p1 = (const float4*)(Opart + ((size_t)NROWS + row) * HD + h * 64);
  float4* po = (float4*)(out + (size_t)row * HD + h * 64);
#pragma unroll
  for (int j = 0; j < 16; ++j) {
    float4 a = p0[j], c = p1[j];
    float4 r;
    r.x = (a.x * e0 + c.x * e1) * inv;
    r.y = (a.y * e0 + c.y * e1) * inv;
    r.z = (a.z * e0 + c.z * e1) * inv;
    r.w = (a.w * e0 + c.w * e1) * inv;
    po[j] = r;
  }
}

extern "C" void kernel_launch(void* const* d_in, const int* in_sizes, int n_in,
                              void* d_out, int out_size, void* d_ws, size_t ws_size,
                              hipStream_t stream) {
  const float* x  = (const float*)d_in[0];
  const float* Wq = (const float*)d_in[1];
  const float* bq = (const float*)d_in[2];
  const float* Wk = (const float*)d_in[3];
  const float* bk = (const float*)d_in[4];
  const float* Wv = (const float*)d_in[5];
  const float* bv = (const float*)d_in[6];
  float* out = (float*)d_out;

  // workspace layout (~30 MiB)
  __bf16* Qb = (__bf16*)d_ws;                        // 16384x128 bf16 each
  __bf16* Kb = Qb + (size_t)NROWS * HD;
  __bf16* Vb = Kb + (size_t)NROWS * HD;
  __bf16* Wb = Vb + (size_t)NROWS * HD;              // 3 x 128 x 2048 bf16
  float*  Opart = (float*)(Wb + (size_t)3 * HD * NEMB);  // 2 x 16384 x 128 fp32
  float*  Ml    = Opart + (size_t)2 * NROWS * HD;        // 2 x 16384 x 2 fp32

  wconv_kernel<<<dim3(3 * 64), dim3(256), 0, stream>>>(Wq, Wk, Wv, Wb);
  qkv_proj_kernel<<<dim3(256 * 3), dim3(256), 0, stream>>>(
      x, Wb, bq, bk, bv, Qb, Kb, Vb);
  attn_kernel<<<dim3(BATCH * 32 * 2), dim3(256), 0, stream>>>(Qb, Kb, Vb, Opart, Ml);
  combine_kernel<<<dim3(NROWS * 2 / 256), dim3(256), 0, stream>>>(Opart, Ml, out);
}